// Round 8
// baseline (81.585 us; speedup 1.0000x reference)
//
#include <hip/hip_runtime.h>

// Static config (matches reference)
#define HP 24
#define WP 24
#define TF 9
#define HW (HP * WP)        // 576
#define DIM 768
#define D4 (DIM / 4)        // 192 groups of 4 elements per row
#define BATCH 4
#define NBOX 50
#define ROI_L (HP * WP)     // 576
#define ROWS_PB 8           // rows per gather block
#define LGROUPS (ROI_L / ROWS_PB)  // 72

typedef float v4f __attribute__((ext_vector_type(4)));

// fp32 -> bf16 round-to-nearest-even (no NaN inputs in this problem)
__device__ __forceinline__ unsigned short f2bf(float f) {
    unsigned u = __float_as_uint(f);
    unsigned rounding = 0x7FFFu + ((u >> 16) & 1u);
    return (unsigned short)((u + rounding) >> 16);
}

// ---------------------------------------------------------------------------
// Kernel 1: temporal mean  [B, HW*T, D] -> sp (bf16) [B, HW, D]
// (identical to R5/R7)
// ---------------------------------------------------------------------------
__global__ void __launch_bounds__(256)
temporal_mean_kernel(const float* __restrict__ in, ushort4* __restrict__ sp) {
    int i = blockIdx.x * blockDim.x + threadIdx.x;
    const int total = BATCH * HW * D4;
    if (i >= total) return;
    int d4 = i % D4;
    int rest = i / D4;
    int hw = rest % HW;
    int b = rest / HW;

    const float4* src =
        (const float4*)(in + ((size_t)(b * HW * TF + hw * TF)) * DIM) + d4;
    float4 acc = make_float4(0.f, 0.f, 0.f, 0.f);
#pragma unroll
    for (int t = 0; t < TF; ++t) {
        float4 v = src[(size_t)t * D4];
        acc.x += v.x; acc.y += v.y; acc.z += v.z; acc.w += v.w;
    }
    acc.x /= 9.0f; acc.y /= 9.0f; acc.z /= 9.0f; acc.w /= 9.0f;

    ushort4 o;
    o.x = f2bf(acc.x); o.y = f2bf(acc.y); o.z = f2bf(acc.z); o.w = f2bf(acc.w);
    sp[i] = o;
}

// ---------------------------------------------------------------------------
// Kernel 2: ROI gather + mask. Same dataflow and cache policy as R7
// (bf16 sp reads cached, out_feat NT stores, mask cached), but:
//  - 8 rows per block (14400 blocks instead of 28800): halves per-block
//    overhead (bbox load latency, geometry VALU, scheduling)
//  - explicit two-phase body: all 8 sp loads issued first (8 independent
//    loads in flight), then 8 convert+NT-store pairs
//  - mask written by lanes 0..7 as one contiguous 32B segment
// ---------------------------------------------------------------------------
__global__ void __launch_bounds__(192)
roi_gather_kernel(const ushort4* __restrict__ sp, const float* __restrict__ bboxes,
                  float* __restrict__ out_feat, float* __restrict__ out_mask) {
    int bid = blockIdx.x;           // [0, B*N*LGROUPS)
    int lg = bid % LGROUPS;
    int rest = bid / LGROUPS;
    int n = rest % NBOX;
    int b = rest / NBOX;
    int tid = threadIdx.x;          // 0..191

    float4 bb = ((const float4*)bboxes)[b * NBOX + n];
    float cx = bb.x, cy = bb.y, bw = bb.z, bh = bb.w;
    float bwp = bw * 1.2f;
    float bhp = bh * 1.2f;

    // astype(int32) truncates toward zero == C (int) cast
    int col_start = max((int)((cx - bwp * 0.5f) * (float)WP), 0);
    int col_end   = min((int)((cx + bwp * 0.5f) * (float)WP), WP);
    int row_start = max((int)((cy - bhp * 0.5f) * (float)HP), 0);
    int row_end   = min((int)((cy + bhp * 0.5f) * (float)HP), HP);

    // (a+b)/2 then trunc; a,b >= 0 so >>1 is exact
    int col_mid = (col_start + col_end) >> 1;
    int row_mid = (row_start + row_end) >> 1;
    // half_min = MIN_PATCHES/2 = 1
    col_start = min(col_start, max(col_mid - 1, 0));
    col_end   = max(col_end,   min(col_mid + 2, WP));
    row_start = min(row_start, max(row_mid - 1, 0));
    row_end   = max(row_end,   min(row_mid + 2, HP));

    int h = max(row_end - row_start, 0);
    int w = max(col_end - col_start, 0);
    int area = h * w;
    int wsafe = max(w, 1);

    int base_l = lg * ROWS_PB;
    size_t out_base = (size_t)(b * NBOX + n) * ROI_L;  // in rows
    v4f* outf4 = (v4f*)out_feat;

    // Phase 1: issue all 8 sp loads (independent, deep MLP)
    ushort4 u[ROWS_PB];
#pragma unroll
    for (int s = 0; s < ROWS_PB; ++s) {
        int l = base_l + s;
        if (l < area) {
            int r = row_start + l / wsafe;
            int c = col_start + l % wsafe;
            // valid => r,c in [0,23]; reference clip is a no-op here.
            u[s] = sp[(size_t)(b * HW + r * WP + c) * D4 + tid];
        }
    }

    // Phase 2: convert + NT store
#pragma unroll
    for (int s = 0; s < ROWS_PB; ++s) {
        int l = base_l + s;
        v4f v = (v4f)(0.f);
        if (l < area) {
            // bf16 -> fp32 is an exact bit shift
            v.x = __uint_as_float((unsigned)u[s].x << 16);
            v.y = __uint_as_float((unsigned)u[s].y << 16);
            v.z = __uint_as_float((unsigned)u[s].z << 16);
            v.w = __uint_as_float((unsigned)u[s].w << 16);
        }
        __builtin_nontemporal_store(v, &outf4[(out_base + l) * D4 + tid]);
    }

    // Mask: lanes 0..7 write one contiguous 32B segment
    if (tid < ROWS_PB) {
        int l = base_l + tid;
        out_mask[out_base + l] = (l < area) ? 0.0f : 1.0f;  // True(=1) = padding
    }
}

extern "C" void kernel_launch(void* const* d_in, const int* in_sizes, int n_in,
                              void* d_out, int out_size, void* d_ws, size_t ws_size,
                              hipStream_t stream) {
    const float* spatial = (const float*)d_in[0];   // [B, HW*T, D] fp32
    const float* bboxes  = (const float*)d_in[1];   // [B, N, 4] fp32

    ushort4* sp = (ushort4*)d_ws;                   // [B, HW, D] bf16 (3.5 MB)

    float* out_feat = (float*)d_out;                               // [B,N,L,D]
    float* out_mask = (float*)d_out + (size_t)BATCH * NBOX * ROI_L * DIM;  // [B,N,L]

    {
        int total = BATCH * HW * D4;            // 442368
        int block = 256;
        int grid = (total + block - 1) / block; // 1728
        temporal_mean_kernel<<<grid, block, 0, stream>>>(spatial, sp);
    }
    {
        int grid = BATCH * NBOX * LGROUPS;      // 14400
        roi_gather_kernel<<<grid, 192, 0, stream>>>(sp, bboxes, out_feat, out_mask);
    }
}